// Round 3
// baseline (141.752 us; speedup 1.0000x reference)
//
#include <hip/hip_runtime.h>

// RelationModule: out = ((psi @ M - diag(psi·phi)·u) / N) @ w_r + x
// where M[b] = phi[b]^T @ u[b]  (F×F per batch) — avoids the O(N^2) score matrix.
//
// B=32, N=2048, F=32. fp32 throughout.
//
// R3: weights/biases/M are BLOCK-UNIFORM — read them straight from global so
// the compiler scalarizes to s_load (SGPR + K$), freeing the LDS/vector-mem
// pipe entirely. R1/R2 staged them in LDS: ~1280 wave-uniform ds_read_b128
// per wave = ~25 µs of LDS issue per CU — that was the bottleneck
// (VALUBusy 16%, LDS pipe saturated with broadcasts).
// LDS is kept ONLY where lanes read different addresses (k1 phase-B transpose).

namespace {
constexpr int kF = 32;
constexpr int kN = 2048;
constexpr int kB = 32;

constexpr int kChunk1 = 128;              // elements per k_partial_m block (128 threads)
constexpr int kNChunk1 = kN / kChunk1;    // 16
constexpr int kChunk2 = 256;              // elements per k_relation block (256 threads)
constexpr int kNChunk2 = kN / kChunk2;    // 8

constexpr int kPad = 36;                  // LDS row stride (floats): 144 B, 16B-aligned
}

// ---------------------------------------------------------------------------
// Kernel 1: per-batch M = phi^T @ relu(u), accumulated via atomicAdd partials.
// Grid (kNChunk1, kB), 128 threads. Phase A: thread-per-element embeddings
// (weights via s_load). Phase B: LDS transpose + outer-product reduction.
// ---------------------------------------------------------------------------
__global__ __launch_bounds__(128, 1) void k_partial_m(
    const float* __restrict__ x,
    const float* __restrict__ w_phi, const float* __restrict__ b_phi,
    const float* __restrict__ w_u,   const float* __restrict__ b_u,
    float* __restrict__ m_out)  // [kB][kF*kF], pre-zeroed
{
    __shared__ float phi_s[kChunk1 * kPad];
    __shared__ float u_s[kChunk1 * kPad];

    const int tid = threadIdx.x;
    const int c = blockIdx.x;
    const int b = blockIdx.y;

    // ---- Phase A: one thread per element: phi_j, relu(u_j) -> LDS ----
    const size_t base = ((size_t)b * kN + (size_t)c * kChunk1 + tid) * kF;
    float xs[kF];
#pragma unroll
    for (int k = 0; k < kF / 4; ++k) {
        float4 v = ((const float4*)(x + base))[k];
        xs[4 * k + 0] = v.x; xs[4 * k + 1] = v.y;
        xs[4 * k + 2] = v.z; xs[4 * k + 3] = v.w;
    }

    float ph[kF], uu[kF];
#pragma unroll
    for (int g = 0; g < kF; ++g) {
        ph[g] = b_phi[g];        // uniform -> s_load
        uu[g] = b_u[g];
    }
#pragma unroll
    for (int f = 0; f < kF; ++f) {
        const float xf = xs[f];
#pragma unroll
        for (int g = 0; g < kF; ++g) {
            ph[g] = fmaf(xf, w_phi[f * kF + g], ph[g]);  // uniform idx -> s_load
            uu[g] = fmaf(xf, w_u[f * kF + g], uu[g]);
        }
    }

    float* prow = phi_s + tid * kPad;
    float* urow = u_s + tid * kPad;
#pragma unroll
    for (int g4 = 0; g4 < kF / 4; ++g4) {
        float4 pv = make_float4(ph[4 * g4], ph[4 * g4 + 1], ph[4 * g4 + 2], ph[4 * g4 + 3]);
        float4 uv = make_float4(fmaxf(uu[4 * g4], 0.f), fmaxf(uu[4 * g4 + 1], 0.f),
                                fmaxf(uu[4 * g4 + 2], 0.f), fmaxf(uu[4 * g4 + 3], 0.f));
        *((float4*)prow + g4) = pv;
        *((float4*)urow + g4) = uv;
    }
    __syncthreads();

    // ---- Phase B: thread -> (f, 8 consecutive g). 32*4 = 128 threads cover 32x32.
    // Lane-varying LDS reads: the legitimate use of the pipe.
    const int f = tid & (kF - 1);
    const int g8 = (tid >> 5) * 8;  // 0,8,16,24
    float acc[8];
#pragma unroll
    for (int k = 0; k < 8; ++k) acc[k] = 0.f;

#pragma unroll 8
    for (int j = 0; j < kChunk1; ++j) {
        const float p = phi_s[j * kPad + f];                 // consecutive over lanes
        const float4 u0 = *(const float4*)(u_s + j * kPad + g8);
        const float4 u1 = *(const float4*)(u_s + j * kPad + g8 + 4);
        acc[0] += p * u0.x; acc[1] += p * u0.y; acc[2] += p * u0.z; acc[3] += p * u0.w;
        acc[4] += p * u1.x; acc[5] += p * u1.y; acc[6] += p * u1.z; acc[7] += p * u1.w;
    }

    float* mdst = m_out + (size_t)b * kF * kF + f * kF + g8;
#pragma unroll
    for (int k = 0; k < 8; ++k) atomicAdd(mdst + k, acc[k]);
}

// ---------------------------------------------------------------------------
// Kernel 2: thread-per-element: psi, phi, u, att = psi@M - diag*u,
//           out = (att/N) @ w_r + x.  Grid (kNChunk2, kB), 256 threads.
// NO LDS: every weight/bias/M access is block-uniform -> s_load via K$.
// ---------------------------------------------------------------------------
__global__ __launch_bounds__(256, 1) void k_relation(
    const float* __restrict__ x,
    const float* __restrict__ w_psi, const float* __restrict__ b_psi,
    const float* __restrict__ w_phi, const float* __restrict__ b_phi,
    const float* __restrict__ w_u,   const float* __restrict__ b_u,
    const float* __restrict__ w_r,
    const float* __restrict__ m_in,   // [kB][kF*kF]
    float* __restrict__ out)
{
    const int tid = threadIdx.x;
    const int c = blockIdx.x;
    const int b = blockIdx.y;
    const float* __restrict__ m_b = m_in + (size_t)b * kF * kF;  // uniform base

    const size_t base = ((size_t)b * kN + (size_t)c * kChunk2 + tid) * kF;
    float xs[kF];
#pragma unroll
    for (int k = 0; k < kF / 4; ++k) {
        float4 v = ((const float4*)(x + base))[k];
        xs[4 * k + 0] = v.x; xs[4 * k + 1] = v.y;
        xs[4 * k + 2] = v.z; xs[4 * k + 3] = v.w;
    }

    // ---- fused: psi, phi, u in one f-loop; weights via s_load ----
    float ps[kF], ph[kF], uu[kF];
#pragma unroll
    for (int g = 0; g < kF; ++g) {
        ps[g] = b_psi[g];
        ph[g] = b_phi[g];
        uu[g] = b_u[g];
    }
#pragma unroll
    for (int f = 0; f < kF; ++f) {
        const float xf = xs[f];
#pragma unroll
        for (int g = 0; g < kF; ++g) {
            ps[g] = fmaf(xf, w_psi[f * kF + g], ps[g]);
            ph[g] = fmaf(xf, w_phi[f * kF + g], ph[g]);
            uu[g] = fmaf(xf, w_u[f * kF + g], uu[g]);
        }
    }

    // diag = psi . phi ; u = relu(u). ph dead after this.
    float diag = 0.f;
#pragma unroll
    for (int g = 0; g < kF; ++g) diag += ps[g] * ph[g];
#pragma unroll
    for (int g = 0; g < kF; ++g) uu[g] = fmaxf(uu[g], 0.f);

    // att = psi @ M - diag * u
    float at[kF];
#pragma unroll
    for (int g = 0; g < kF; ++g) at[g] = -diag * uu[g];
#pragma unroll
    for (int f = 0; f < kF; ++f) {
        const float psf = ps[f];
#pragma unroll
        for (int g = 0; g < kF; ++g) {
            at[g] = fmaf(psf, m_b[f * kF + g], at[g]);
        }
    }

    // out = (att / N) @ w_r + x  — accumulate in place into xs
    const float inv_n = 1.0f / (float)kN;
#pragma unroll
    for (int g = 0; g < kF; ++g) {
        const float ag = at[g] * inv_n;
#pragma unroll
        for (int f = 0; f < kF; ++f) {
            xs[f] = fmaf(ag, w_r[g * kF + f], xs[f]);
        }
    }

#pragma unroll
    for (int k = 0; k < kF / 4; ++k) {
        float4 v = make_float4(xs[4 * k], xs[4 * k + 1], xs[4 * k + 2], xs[4 * k + 3]);
        ((float4*)(out + base))[k] = v;
    }
}

extern "C" void kernel_launch(void* const* d_in, const int* in_sizes, int n_in,
                              void* d_out, int out_size, void* d_ws, size_t ws_size,
                              hipStream_t stream) {
    const float* x     = (const float*)d_in[0];
    const float* w_psi = (const float*)d_in[1];
    const float* b_psi = (const float*)d_in[2];
    const float* w_phi = (const float*)d_in[3];
    const float* b_phi = (const float*)d_in[4];
    const float* w_u   = (const float*)d_in[5];
    const float* b_u   = (const float*)d_in[6];
    const float* w_r   = (const float*)d_in[7];
    float* out = (float*)d_out;
    float* m_ws = (float*)d_ws;  // kB * kF * kF floats = 128 KiB

    // d_ws is poisoned 0xAA before every timed launch — zero the M accumulators.
    hipMemsetAsync(d_ws, 0, (size_t)kB * kF * kF * sizeof(float), stream);

    k_partial_m<<<dim3(kNChunk1, kB), 128, 0, stream>>>(
        x, w_phi, b_phi, w_u, b_u, m_ws);
    k_relation<<<dim3(kNChunk2, kB), 256, 0, stream>>>(
        x, w_psi, b_psi, w_phi, b_phi, w_u, b_u, w_r, m_ws, out);
}

// Round 4
// 83.338 us; speedup vs baseline: 1.7009x; 1.7009x over previous
//
#include <hip/hip_runtime.h>

// RelationModule via MFMA: out = x + ((psi@M - diag(psi*phi)*u)/N) @ w_r,
// M[b] = phi[b]^T @ relu(u[b])  (32x32 per batch).  B=32, N=2048, F=32.
//
// R4: bf16 MFMA (v_mfma_f32_32x32x16_bf16) for all six 32-deep contractions.
// Everything in k2 is computed TRANSPOSED (psi^T = W_psi^T @ x^T) so the
// C-layout (col = lane&31) carries the ELEMENT index in lanes:
//   - diag = one in-register reduction + one shfl_xor(32)
//   - C -> next-MFMA operand (k = C-row) needs only 8 packed shfl_xor(32) + selects
// fp32 residual x is added exactly; bf16 only touches the /N-scaled correction.
//
// Layouts used (gfx950):
//   C/D 32x32: col = lane&31, row = (reg&3) + 8*(reg>>2) + 4*(lane>>5)   [verified m74/m101]
//   A 32x16:   m = lane&31,  k = 8*(lane>>5) + j   (j=0..7, 4 VGPRs bf16)  [inferred, std]
//   B 16x32:   n = lane&31,  k = 8*(lane>>5) + j                           [inferred, std]

namespace {
constexpr int kF = 32;
constexpr int kN = 2048;
constexpr int kB = 32;
}

typedef __attribute__((ext_vector_type(8))) short bf16x8;
typedef __attribute__((ext_vector_type(16))) float f32x16;

union BF8 { bf16x8 v; int i[4]; };

__device__ inline unsigned short f2bf(float f) {
    union { float f; unsigned int u; } c; c.f = f;
    unsigned int r = c.u + 0x7FFFu + ((c.u >> 16) & 1u);   // RNE
    return (unsigned short)(r >> 16);
}
__device__ inline int pk2(float lo, float hi) {
    return (int)f2bf(lo) | ((int)f2bf(hi) << 16);
}

// Operand frag of Mat where K indexes Mat's ROWS and lane&31 indexes Mat's cols.
// Serves A = Mat^T (m = col) and B = Mat (n = col) identically.
// frag element j of f0: Mat[8h + j][col]; of f1: Mat[16 + 8h + j][col].
__device__ inline void load_wfrags(const float* __restrict__ W, int col, int h,
                                   bf16x8& f0, bf16x8& f1) {
    BF8 a, b;
#pragma unroll
    for (int q = 0; q < 4; ++q)
        a.i[q] = pk2(W[(8 * h + 2 * q) * kF + col], W[(8 * h + 2 * q + 1) * kF + col]);
#pragma unroll
    for (int q = 0; q < 4; ++q)
        b.i[q] = pk2(W[(16 + 8 * h + 2 * q) * kF + col], W[(16 + 8 * h + 2 * q + 1) * kF + col]);
    f0 = a.v; f1 = b.v;
}

// x operand: element j of fi = x[row][16*fi + 8h + j]  (row = this lane's element).
// Same bytes serve A = x (k1) and B = x^T (k2).
__device__ inline void load_xfrags(const float* __restrict__ xr, int h,
                                   bf16x8& f0, bf16x8& f1) {
    float4 a = *(const float4*)(xr + 8 * h);
    float4 b = *(const float4*)(xr + 8 * h + 4);
    float4 c = *(const float4*)(xr + 16 + 8 * h);
    float4 d = *(const float4*)(xr + 16 + 8 * h + 4);
    BF8 u0, u1;
    u0.i[0] = pk2(a.x, a.y); u0.i[1] = pk2(a.z, a.w);
    u0.i[2] = pk2(b.x, b.y); u0.i[3] = pk2(b.z, b.w);
    u1.i[0] = pk2(c.x, c.y); u1.i[1] = pk2(c.z, c.w);
    u1.i[2] = pk2(d.x, d.y); u1.i[3] = pk2(d.z, d.w);
    f0 = u0.v; f1 = u1.v;
}

// C-layout regs (16 fp32) -> operand frags where K = C-row, col stays lane&31.
// Row map: row(r,h) = (r&3) + 8*(r>>2) + 4h.  Cross-half values via shfl_xor(32)
// on PACKED bf16 pairs (dword q = rows of regs 2q,2q+1).
__device__ inline void c_to_kfrags(const f32x16& v, int h, bf16x8& f0, bf16x8& f1) {
    int p[8], t[8];
#pragma unroll
    for (int q = 0; q < 8; ++q) p[q] = pk2(v[2 * q], v[2 * q + 1]);
#pragma unroll
    for (int q = 0; q < 8; ++q) t[q] = __shfl_xor(p[q], 32, 64);
    BF8 a, b;
    // k-chunk 0 (rows 0..15): own regs 0-7 hold rows {0-3,8-11}+4h, partner fills the rest
    a.i[0] = h ? t[2] : p[0];
    a.i[1] = h ? t[3] : p[1];
    a.i[2] = h ? p[2] : t[0];
    a.i[3] = h ? p[3] : t[1];
    // k-chunk 1 (rows 16..31): regs 8-15
    b.i[0] = h ? t[6] : p[4];
    b.i[1] = h ? t[7] : p[5];
    b.i[2] = h ? p[6] : t[4];
    b.i[3] = h ? p[7] : t[5];
    f0 = a.v; f1 = b.v;
}

__device__ inline f32x16 zero16() {
    f32x16 z;
#pragma unroll
    for (int i = 0; i < 16; ++i) z[i] = 0.f;
    return z;
}

#define MFMA(A, B, C) __builtin_amdgcn_mfma_f32_32x32x16_bf16(A, B, C, 0, 0, 0)

// ---------------------------------------------------------------------------
// Kernel 1: M[b] = phi^T @ relu(u).  Grid 512 x 256: wave = one 32-el tile,
// block = 4 tiles of one batch. Per wave: phi = x@W_phi, u = relu(x@W_u)
// (normal orientation: C col = g), then M-tile = mfma(phi^T-frags, u-frags).
// Block-reduces 4 waves in LDS, then 4 atomicAdds per thread.
// ---------------------------------------------------------------------------
__global__ __launch_bounds__(256, 2) void k_partial_m(
    const float* __restrict__ x,
    const float* __restrict__ w_phi, const float* __restrict__ b_phi,
    const float* __restrict__ w_u,   const float* __restrict__ b_u,
    float* __restrict__ m_out)  // [kB][kF*kF], pre-zeroed
{
    __shared__ float red_s[4][64 * 20];   // stride 20 floats: conflict-free b128

    const int tid = threadIdx.x;
    const int lane = tid & 63;
    const int w = tid >> 6;
    const int col = lane & 31;            // = g (C col) and operand col
    const int h = lane >> 5;

    const int row0 = blockIdx.x * 128 + w * 32;      // 128 | 2048: block stays in-batch
    const int b = row0 >> 11;

    // A = x frags (m = el = col + row0)
    bf16x8 ax0, ax1;
    load_xfrags(x + (size_t)(row0 + col) * kF, h, ax0, ax1);
    // B = W frags
    bf16x8 bp0, bp1, bu0, bu1;
    load_wfrags(w_phi, col, h, bp0, bp1);
    load_wfrags(w_u,   col, h, bu0, bu1);

    f32x16 phiC = zero16(), uC = zero16();
    phiC = MFMA(ax0, bp0, phiC); phiC = MFMA(ax1, bp1, phiC);
    uC   = MFMA(ax0, bu0, uC);   uC   = MFMA(ax1, bu1, uC);

    const float bphi = b_phi[col];
    const float bu = b_u[col];
#pragma unroll
    for (int r = 0; r < 16; ++r) {
        phiC[r] += bphi;
        uC[r] = fmaxf(uC[r] + bu, 0.f);
    }

    // M-tile += phi^T(32f x 32el) @ u(32el x 32g): K = el via c_to_kfrags
    bf16x8 ap0, ap1, bfu0, bfu1;
    c_to_kfrags(phiC, h, ap0, ap1);
    c_to_kfrags(uC, h, bfu0, bfu1);
    f32x16 macc = zero16();
    macc = MFMA(ap0, bfu0, macc);
    macc = MFMA(ap1, bfu1, macc);   // C: col = g, row = f

    // block reduction: 4 waves -> 1, then atomics
    float* rs = red_s[w] + lane * 20;
#pragma unroll
    for (int q = 0; q < 4; ++q) {
        float4 v = make_float4(macc[4 * q], macc[4 * q + 1], macc[4 * q + 2], macc[4 * q + 3]);
        *(float4*)(rs + 4 * q) = v;
    }
    __syncthreads();

    // thread t: lane' = t>>2, regs r = 4*(t&3) .. +3
    const int lp = tid >> 2;
    const int q = tid & 3;
    float4 s = make_float4(0.f, 0.f, 0.f, 0.f);
#pragma unroll
    for (int ww = 0; ww < 4; ++ww) {
        float4 v = *(const float4*)(red_s[ww] + lp * 20 + 4 * q);
        s.x += v.x; s.y += v.y; s.z += v.z; s.w += v.w;
    }
    const int g = lp & 31;
    const int hp = lp >> 5;
    const int f0 = 8 * q + 4 * hp;        // rows f0..f0+3 (row map with r&3 = 0..3)
    float* mdst = m_out + (size_t)b * kF * kF + (size_t)f0 * kF + g;
    atomicAdd(mdst,            s.x);
    atomicAdd(mdst + kF,       s.y);
    atomicAdd(mdst + 2 * kF,   s.z);
    atomicAdd(mdst + 3 * kF,   s.w);
}

// ---------------------------------------------------------------------------
// Kernel 2: per 32-el tile (one wave, no barriers):
//   psi^T/phi^T/u^T = W^T @ x^T   (C: col = el)
//   diag = per-lane dot + shfl_xor(32)
//   att^T = M^T @ psi^T ; att' = (att^T - diag*u^T)/N
//   corr^T = w_r^T @ att'^T ; out = x + corr  (per-wave LDS transpose for store)
// ---------------------------------------------------------------------------
__global__ __launch_bounds__(256, 2) void k_relation(
    const float* __restrict__ x,
    const float* __restrict__ w_psi, const float* __restrict__ b_psi,
    const float* __restrict__ w_phi, const float* __restrict__ b_phi,
    const float* __restrict__ w_u,   const float* __restrict__ b_u,
    const float* __restrict__ w_r,
    const float* __restrict__ m_in,   // [kB][kF*kF]
    float* __restrict__ out)
{
    __shared__ float t_s[4][32 * 36];     // per-wave transpose scratch (barrier-free)

    const int tid = threadIdx.x;
    const int lane = tid & 63;
    const int w = tid >> 6;
    const int col = lane & 31;            // = el (C col in transposed orientation)
    const int h = lane >> 5;

    const int row0 = blockIdx.x * 128 + w * 32;
    const int b = row0 >> 11;
    const float* __restrict__ m_b = m_in + (size_t)b * kF * kF;

    // B = x^T frags (n = el = col + row0) — same bytes as k1's A = x
    bf16x8 bx0, bx1;
    load_xfrags(x + (size_t)(row0 + col) * kF, h, bx0, bx1);

    // A = W^T frags (m = output feature = col)
    bf16x8 aps0, aps1, aph0, aph1, au0, au1;
    load_wfrags(w_psi, col, h, aps0, aps1);
    load_wfrags(w_phi, col, h, aph0, aph1);
    load_wfrags(w_u,   col, h, au0, au1);

    f32x16 psiT = zero16(), phiT = zero16(), uT = zero16();
    psiT = MFMA(aps0, bx0, psiT); psiT = MFMA(aps1, bx1, psiT);
    phiT = MFMA(aph0, bx0, phiT); phiT = MFMA(aph1, bx1, phiT);
    uT   = MFMA(au0,  bx0, uT);   uT   = MFMA(au1,  bx1, uT);

    // biases: row g(r,h) = (r&3)+8*(r>>2)+4h  (uniform pair per reg -> s_load+cndmask)
#pragma unroll
    for (int r = 0; r < 16; ++r) {
        const int g = (r & 3) + 8 * (r >> 2);
        psiT[r] += h ? b_psi[g + 4] : b_psi[g];
        phiT[r] += h ? b_phi[g + 4] : b_phi[g];
        uT[r] = fmaxf(uT[r] + (h ? b_u[g + 4] : b_u[g]), 0.f);
    }

    // diag[el]: sum over g = own 16 regs + partner half
    float d = 0.f;
#pragma unroll
    for (int r = 0; r < 16; ++r) d += psiT[r] * phiT[r];
    d += __shfl_xor(d, 32, 64);

    // att^T = M^T @ psi^T
    bf16x8 am0, am1, bps0, bps1;
    load_wfrags(m_b, col, h, am0, am1);         // A = M^T
    c_to_kfrags(psiT, h, bps0, bps1);           // B = psi^T (K = g)
    f32x16 attT = zero16();
    attT = MFMA(am0, bps0, attT);
    attT = MFMA(am1, bps1, attT);               // C: col = el, row = g'

    // att' = (att - diag*u)/N  (rows of attT and uT follow the same map)
    const float inv_n = 1.0f / (float)kN;
#pragma unroll
    for (int r = 0; r < 16; ++r) attT[r] = (attT[r] - d * uT[r]) * inv_n;

    // corr^T = w_r^T @ att'^T
    bf16x8 ar0, ar1, bt0, bt1;
    load_wfrags(w_r, col, h, ar0, ar1);         // A = w_r^T
    c_to_kfrags(attT, h, bt0, bt1);             // B = att'^T (K = g')
    f32x16 corrT = zero16();
    corrT = MFMA(ar0, bt0, corrT);
    corrT = MFMA(ar1, bt1, corrT);              // C: col = el, row = h'

    // store: LDS transpose [el][h'] then coalesced float4 + fp32 residual
    float* ts = t_s[w];
#pragma unroll
    for (int q = 0; q < 4; ++q) {
        float4 v = make_float4(corrT[4 * q], corrT[4 * q + 1], corrT[4 * q + 2], corrT[4 * q + 3]);
        *(float4*)(ts + col * 36 + 8 * q + 4 * h) = v;   // rows 8q+4h .. +3
    }
    // wave-local: ds ops complete in order; compiler inserts lgkmcnt before reads
    const size_t gbase = (size_t)row0 * kF;
#pragma unroll
    for (int q = 0; q < 4; ++q) {
        const int idx = q * 256 + lane * 4;              // 0..1023 over the tile
        const int el = idx >> 5;
        const int c = idx & 31;
        float4 cv = *(const float4*)(ts + el * 36 + c);
        float4 xv = *(const float4*)(x + gbase + idx);
        float4 o = make_float4(xv.x + cv.x, xv.y + cv.y, xv.z + cv.z, xv.w + cv.w);
        *(float4*)(out + gbase + idx) = o;
    }
}

extern "C" void kernel_launch(void* const* d_in, const int* in_sizes, int n_in,
                              void* d_out, int out_size, void* d_ws, size_t ws_size,
                              hipStream_t stream) {
    const float* x     = (const float*)d_in[0];
    const float* w_psi = (const float*)d_in[1];
    const float* b_psi = (const float*)d_in[2];
    const float* w_phi = (const float*)d_in[3];
    const float* b_phi = (const float*)d_in[4];
    const float* w_u   = (const float*)d_in[5];
    const float* b_u   = (const float*)d_in[6];
    const float* w_r   = (const float*)d_in[7];
    float* out = (float*)d_out;
    float* m_ws = (float*)d_ws;  // kB * kF * kF floats = 128 KiB

    // d_ws is poisoned 0xAA before every timed launch — zero the M accumulators.
    hipMemsetAsync(d_ws, 0, (size_t)kB * kF * kF * sizeof(float), stream);

    // 65536 elements / 32 per wave / 4 waves per block = 512 blocks each
    k_partial_m<<<dim3(512), 256, 0, stream>>>(x, w_phi, b_phi, w_u, b_u, m_ws);
    k_relation<<<dim3(512), 256, 0, stream>>>(x, w_psi, b_psi, w_phi, b_phi,
                                              w_u, b_u, w_r, m_ws, out);
}